// Round 3
// baseline (136.115 us; speedup 1.0000x reference)
//
#include <hip/hip_runtime.h>
#include <stdint.h>

// Problem constants
#define D_DIM 512
#define B_ROWS 4096
#define N_ROWS 8192
// (1/TEMPERATURE) * log2(e) : exp(x/T) == exp2(x * SCALE_L2E)
#define SCALE_L2E 14.426950408889634f

#define BM 128
#define BK 64
#define KCHUNKS (D_DIM / BK)        // 8
#define NT (N_ROWS / BM)            // 64 tile rows/cols
#define NPAIRS (NT * (NT + 1) / 2)  // 2080
#define TPB 4                       // tiles per block
#define NBLK (NPAIRS / TPB)         // 520, divisible by 8

typedef __attribute__((ext_vector_type(8))) __bf16 bf16x8;
typedef __attribute__((ext_vector_type(4))) float f32x4;

using gas1_t = const __attribute__((address_space(1))) void;
using las3_t = __attribute__((address_space(3))) void;
#define GLOAD16(g, l) __builtin_amdgcn_global_load_lds((gas1_t*)(g), (las3_t*)(l), 16, 0, 0)

// round-to-nearest-even float -> bf16 bits
__device__ __forceinline__ unsigned int f2bf(float f) {
    union { float f; unsigned int u; } v; v.f = f;
    unsigned int u = v.u;
    return (u + 0x7FFFu + ((u >> 16) & 1u)) >> 16;
}

// ---------------- K1: normalize rows -> bf16 Zn, write positive-pair logits ----------------
__global__ __launch_bounds__(256) void k_normalize(const float* __restrict__ zi,
                                                   const float* __restrict__ zj,
                                                   unsigned short* __restrict__ Zn,
                                                   float* __restrict__ pos) {
    const int t = threadIdx.x;
    const int lane = t & 63;
    const int i = blockIdx.x * 4 + (t >> 6);
    const float* pa = zi + (size_t)i * D_DIM + lane * 8;
    const float* pb = zj + (size_t)i * D_DIM + lane * 8;
    const float4 a0 = *(const float4*)pa;
    const float4 a1 = *(const float4*)(pa + 4);
    const float4 b0 = *(const float4*)pb;
    const float4 b1 = *(const float4*)(pb + 4);
    float ssi = a0.x*a0.x + a0.y*a0.y + a0.z*a0.z + a0.w*a0.w
              + a1.x*a1.x + a1.y*a1.y + a1.z*a1.z + a1.w*a1.w;
    float ssj = b0.x*b0.x + b0.y*b0.y + b0.z*b0.z + b0.w*b0.w
              + b1.x*b1.x + b1.y*b1.y + b1.z*b1.z + b1.w*b1.w;
    float dt  = a0.x*b0.x + a0.y*b0.y + a0.z*b0.z + a0.w*b0.w
              + a1.x*b1.x + a1.y*b1.y + a1.z*b1.z + a1.w*b1.w;
    #pragma unroll
    for (int off = 1; off < 64; off <<= 1) {
        ssi += __shfl_xor(ssi, off);
        ssj += __shfl_xor(ssj, off);
        dt  += __shfl_xor(dt,  off);
    }
    const float si = 1.0f / fmaxf(sqrtf(ssi), 1e-12f);
    const float sj = 1.0f / fmaxf(sqrtf(ssj), 1e-12f);
    uint4 pi, pj;
    pi.x = f2bf(a0.x * si) | (f2bf(a0.y * si) << 16);
    pi.y = f2bf(a0.z * si) | (f2bf(a0.w * si) << 16);
    pi.z = f2bf(a1.x * si) | (f2bf(a1.y * si) << 16);
    pi.w = f2bf(a1.z * si) | (f2bf(a1.w * si) << 16);
    pj.x = f2bf(b0.x * sj) | (f2bf(b0.y * sj) << 16);
    pj.y = f2bf(b0.z * sj) | (f2bf(b0.w * sj) << 16);
    pj.z = f2bf(b1.x * sj) | (f2bf(b1.y * sj) << 16);
    pj.w = f2bf(b1.z * sj) | (f2bf(b1.w * sj) << 16);
    *(uint4*)(Zn + (size_t)i * D_DIM + lane * 8) = pi;
    *(uint4*)(Zn + (size_t)(B_ROWS + i) * D_DIM + lane * 8) = pj;
    if (lane == 0) pos[i] = 20.0f * dt * si * sj;  // positive logit counted twice: 2*dot/T
}

// ---------------- K2: symmetric fused S = Zn·Zn^T + per-row sum(exp(S/T)) -----------------
// TPB tiles (128x128, pairs I<=J) per block; 2-phase double-buffered pipeline: the next
// chunk's global_load_lds issues BEFORE the current chunk's ds_read+MFMA; one
// vmcnt(0)-draining barrier per chunk; pipeline continues across tile boundaries and the
// per-tile epilogue (exp2 + atomics) overlaps the next tile's in-flight loads.
__global__ __launch_bounds__(256) void k_gemm_lse(const unsigned short* __restrict__ Zn,
                                                  float* __restrict__ rowsum_g) {
    __shared__ __align__(16) unsigned short lds[2 * 2 * BM * BK];  // 64 KiB: [buf][A/B]
    const int t    = threadIdx.x;
    const int lane = t & 63;
    const int w    = t >> 6;
    const int wm   = w >> 1, wn = w & 1;
    const int l15  = lane & 15, lhi = lane >> 4;

    // XCD-aware swizzle (bijective: NBLK % 8 == 0), then triangular decode of TPB pairs
    const int g = (blockIdx.x & 7) * (NBLK / 8) + (blockIdx.x >> 3);
    int Ia[TPB], Ja[TPB];
    {
        int b = g * TPB, I = 0;
        while (b >= NT - I) { b -= NT - I; ++I; }
        int J = I + b;
        #pragma unroll
        for (int q = 0; q < TPB; ++q) {
            Ia[q] = I; Ja[q] = J;
            ++J; if (J == NT) { ++I; J = I; }
        }
    }

    // staging geometry: thread t stages 16B of row (h*32 + t>>3), stored slot (t&7);
    // linear LDS dest (row*128 + (t&7)*16), pre-swizzled global source (kseg = slot^row&7)
    const int srow = t >> 3;
    const int slot = t & 7;

    auto stage = [&](int buf, int rowB, int colB, bool dg, int kbase) {
        char* baseA = (char*)lds + buf * 32768;
        char* baseB = baseA + 16384;
        #pragma unroll
        for (int h = 0; h < 4; ++h) {
            const int row  = h * 32 + srow;
            const int kseg = slot ^ (row & 7);
            const unsigned short* ga = Zn + (size_t)(rowB + row) * D_DIM + kbase + kseg * 8;
            GLOAD16(ga, baseA + h * 4096 + t * 16);
            if (!dg) {
                const unsigned short* gb = Zn + (size_t)(colB + row) * D_DIM + kbase + kseg * 8;
                GLOAD16(gb, baseB + h * 4096 + t * 16);
            }
        }
    };

    f32x4 acc[4][4];
    float rowsum[4][4];
    #pragma unroll
    for (int a = 0; a < 4; ++a)
        #pragma unroll
        for (int b = 0; b < 4; ++b) {
            rowsum[a][b] = 0.0f;
            #pragma unroll
            for (int q = 0; q < 4; ++q) acc[a][b][q] = 0.0f;
        }

    auto compute = [&](int buf, bool dg) {
        const char* baseA = (const char*)lds + buf * 32768;
        const char* baseB = dg ? baseA : baseA + 16384;
        #pragma unroll
        for (int ks = 0; ks < 2; ++ks) {
            bf16x8 af[4], bg[4];
            #pragma unroll
            for (int mi = 0; mi < 4; ++mi) {
                const int row   = wm * 64 + mi * 16 + l15;
                const int slotr = (ks * 4 + lhi) ^ (row & 7);   // swizzled read
                af[mi] = *(const bf16x8*)(baseA + row * 128 + slotr * 16);
            }
            #pragma unroll
            for (int ni = 0; ni < 4; ++ni) {
                const int row   = wn * 64 + ni * 16 + l15;
                const int slotr = (ks * 4 + lhi) ^ (row & 7);
                bg[ni] = *(const bf16x8*)(baseB + row * 128 + slotr * 16);
            }
            #pragma unroll
            for (int mi = 0; mi < 4; ++mi)
                #pragma unroll
                for (int ni = 0; ni < 4; ++ni)
                    acc[mi][ni] = __builtin_amdgcn_mfma_f32_16x16x32_bf16(af[mi], bg[ni], acc[mi][ni], 0, 0, 0);
        }
    };

    auto epilogue = [&](int rowB, int colB, bool dg) {
        // C/D layout: col = lane&15, row = (lane>>4)*4 + reg
        if (dg) {
            #pragma unroll
            for (int mi = 0; mi < 4; ++mi) {
                const int grow_base = rowB + wm * 64 + mi * 16 + lhi * 4;
                #pragma unroll
                for (int ni = 0; ni < 4; ++ni) {
                    const int gcol = colB + wn * 64 + ni * 16 + l15;
                    #pragma unroll
                    for (int r = 0; r < 4; ++r) {
                        float arg = acc[mi][ni][r] * SCALE_L2E;
                        if (grow_base + r == gcol) arg = -1e30f;  // exp2 -> 0
                        rowsum[mi][r] += exp2f(arg);
                    }
                }
            }
        } else {
            float colsum[4] = {0.0f, 0.0f, 0.0f, 0.0f};
            #pragma unroll
            for (int mi = 0; mi < 4; ++mi)
                #pragma unroll
                for (int ni = 0; ni < 4; ++ni)
                    #pragma unroll
                    for (int r = 0; r < 4; ++r) {
                        const float e = exp2f(acc[mi][ni][r] * SCALE_L2E);
                        rowsum[mi][r] += e;
                        colsum[ni] += e;
                    }
            #pragma unroll
            for (int ni = 0; ni < 4; ++ni) {
                float c = colsum[ni];
                c += __shfl_xor(c, 16);
                c += __shfl_xor(c, 32);
                if (lhi == 0)
                    atomicAdd(&rowsum_g[colB + wn * 64 + ni * 16 + l15], c);
            }
        }
        #pragma unroll
        for (int mi = 0; mi < 4; ++mi)
            #pragma unroll
            for (int r = 0; r < 4; ++r) {
                float s = rowsum[mi][r];
                s += __shfl_xor(s, 1);
                s += __shfl_xor(s, 2);
                s += __shfl_xor(s, 4);
                s += __shfl_xor(s, 8);
                if (l15 == 0)
                    atomicAdd(&rowsum_g[rowB + wm * 64 + mi * 16 + lhi * 4 + r], s);
            }
        // reset accumulators for the next tile
        #pragma unroll
        for (int a = 0; a < 4; ++a)
            #pragma unroll
            for (int b = 0; b < 4; ++b) {
                rowsum[a][b] = 0.0f;
                #pragma unroll
                for (int q = 0; q < 4; ++q) acc[a][b][q] = 0.0f;
            }
    };

    // prologue: stage tile0 chunk0 into buf0
    stage(0, Ia[0] * BM, Ja[0] * BM, Ia[0] == Ja[0], 0);
    __syncthreads();

    #pragma unroll
    for (int ti = 0; ti < TPB; ++ti) {
        const int rowB = Ia[ti] * BM, colB = Ja[ti] * BM;
        const bool dg = (Ia[ti] == Ja[ti]);
        for (int kc = 0; kc < KCHUNKS; ++kc) {
            const int cur = kc & 1;
            // issue next chunk's loads BEFORE computing the current chunk
            if (kc + 1 < KCHUNKS) {
                stage(cur ^ 1, rowB, colB, dg, (kc + 1) * BK);
            } else if (ti + 1 < TPB) {
                stage(cur ^ 1, Ia[ti + 1] * BM, Ja[ti + 1] * BM,
                      Ia[ti + 1] == Ja[ti + 1], 0);
            }
            compute(cur, dg);
            if (kc == KCHUNKS - 1) epilogue(rowB, colB, dg);
            __syncthreads();  // drains vmcnt(0): next chunk's buffer is complete
        }
    }
}

// ---------------- K3: sums[1] += sum(ln(rowsum_i)); sums[0] += sum(pos) ----------------
__global__ __launch_bounds__(256) void k_lse(const float* __restrict__ rowsum_g,
                                             const float* __restrict__ pos,
                                             float* __restrict__ sums) {
    const int i = blockIdx.x * 256 + threadIdx.x;
    float l = logf(rowsum_g[i]);
    float p = (i < B_ROWS) ? pos[i] : 0.0f;
    #pragma unroll
    for (int off = 1; off < 64; off <<= 1) {
        l += __shfl_xor(l, off);
        p += __shfl_xor(p, off);
    }
    __shared__ float red[2][4];
    if ((threadIdx.x & 63) == 0) {
        red[0][threadIdx.x >> 6] = l;
        red[1][threadIdx.x >> 6] = p;
    }
    __syncthreads();
    if (threadIdx.x == 0) {
        atomicAdd(&sums[1], red[0][0] + red[0][1] + red[0][2] + red[0][3]);
        atomicAdd(&sums[0], red[1][0] + red[1][1] + red[1][2] + red[1][3]);
    }
}

// ---------------- K4: loss = mean(lse) - mean(pos) ----------------
__global__ void k_final(const float* __restrict__ sums, float* __restrict__ out) {
    out[0] = (sums[1] - sums[0]) * (1.0f / (float)N_ROWS);
}

extern "C" void kernel_launch(void* const* d_in, const int* in_sizes, int n_in,
                              void* d_out, int out_size, void* d_ws, size_t ws_size,
                              hipStream_t stream) {
    (void)in_sizes; (void)n_in; (void)out_size; (void)ws_size;
    const float* zi = (const float*)d_in[0];
    const float* zj = (const float*)d_in[1];

    // workspace layout
    const size_t ZN_BYTES = (size_t)N_ROWS * D_DIM * 2;  // 8 MiB bf16
    unsigned short* Zn    = (unsigned short*)d_ws;
    float* rowsum_g       = (float*)((char*)d_ws + ZN_BYTES);                           // 8192 f32
    float* pos            = (float*)((char*)d_ws + ZN_BYTES + N_ROWS * 4);              // 4096 f32
    float* sums           = (float*)((char*)d_ws + ZN_BYTES + N_ROWS * 4 + B_ROWS * 4); // [pos, lse]

    // zero the atomically-accumulated region (rowsum + pos + sums)
    hipMemsetAsync((char*)d_ws + ZN_BYTES, 0, N_ROWS * 4 + B_ROWS * 4 + 16, stream);

    k_normalize<<<B_ROWS / 4, 256, 0, stream>>>(zi, zj, Zn, pos);
    k_gemm_lse<<<NBLK, 256, 0, stream>>>(Zn, rowsum_g);
    k_lse<<<N_ROWS / 256, 256, 0, stream>>>(rowsum_g, pos, sums);
    k_final<<<1, 1, 0, stream>>>(sums, (float*)d_out);
}

// Round 4
// 103.907 us; speedup vs baseline: 1.3100x; 1.3100x over previous
//
#include <hip/hip_runtime.h>
#include <stdint.h>

// Problem constants
#define D_DIM 512
#define B_ROWS 4096
#define N_ROWS 8192
// (1/TEMPERATURE) * log2(e) : exp(x/T) == exp2(x * SCALE_L2E)
#define SCALE_L2E 14.426950408889634f

#define BM 256                      // square tile edge
#define BK 64
#define KCHUNKS (D_DIM / BK)        // 8
#define NT (N_ROWS / BM)            // 32 tile rows/cols
#define NPAIRS (NT * (NT + 1) / 2)  // 528, divisible by 8

typedef __attribute__((ext_vector_type(8))) __bf16 bf16x8;
typedef __attribute__((ext_vector_type(4))) float f32x4;

using gas1_t = const __attribute__((address_space(1))) void;
using las3_t = __attribute__((address_space(3))) void;
#define GLOAD16(g, l) __builtin_amdgcn_global_load_lds((gas1_t*)(g), (las3_t*)(l), 16, 0, 0)

// round-to-nearest-even float -> bf16 bits
__device__ __forceinline__ unsigned int f2bf(float f) {
    union { float f; unsigned int u; } v; v.f = f;
    unsigned int u = v.u;
    return (u + 0x7FFFu + ((u >> 16) & 1u)) >> 16;
}

// ---------------- K1: normalize rows -> bf16 Zn, write positive-pair logits ----------------
__global__ __launch_bounds__(256) void k_normalize(const float* __restrict__ zi,
                                                   const float* __restrict__ zj,
                                                   unsigned short* __restrict__ Zn,
                                                   float* __restrict__ pos) {
    const int t = threadIdx.x;
    const int lane = t & 63;
    const int i = blockIdx.x * 4 + (t >> 6);
    const float* pa = zi + (size_t)i * D_DIM + lane * 8;
    const float* pb = zj + (size_t)i * D_DIM + lane * 8;
    const float4 a0 = *(const float4*)pa;
    const float4 a1 = *(const float4*)(pa + 4);
    const float4 b0 = *(const float4*)pb;
    const float4 b1 = *(const float4*)(pb + 4);
    float ssi = a0.x*a0.x + a0.y*a0.y + a0.z*a0.z + a0.w*a0.w
              + a1.x*a1.x + a1.y*a1.y + a1.z*a1.z + a1.w*a1.w;
    float ssj = b0.x*b0.x + b0.y*b0.y + b0.z*b0.z + b0.w*b0.w
              + b1.x*b1.x + b1.y*b1.y + b1.z*b1.z + b1.w*b1.w;
    float dt  = a0.x*b0.x + a0.y*b0.y + a0.z*b0.z + a0.w*b0.w
              + a1.x*b1.x + a1.y*b1.y + a1.z*b1.z + a1.w*b1.w;
    #pragma unroll
    for (int off = 1; off < 64; off <<= 1) {
        ssi += __shfl_xor(ssi, off);
        ssj += __shfl_xor(ssj, off);
        dt  += __shfl_xor(dt,  off);
    }
    const float si = 1.0f / fmaxf(sqrtf(ssi), 1e-12f);
    const float sj = 1.0f / fmaxf(sqrtf(ssj), 1e-12f);
    uint4 pi, pj;
    pi.x = f2bf(a0.x * si) | (f2bf(a0.y * si) << 16);
    pi.y = f2bf(a0.z * si) | (f2bf(a0.w * si) << 16);
    pi.z = f2bf(a1.x * si) | (f2bf(a1.y * si) << 16);
    pi.w = f2bf(a1.z * si) | (f2bf(a1.w * si) << 16);
    pj.x = f2bf(b0.x * sj) | (f2bf(b0.y * sj) << 16);
    pj.y = f2bf(b0.z * sj) | (f2bf(b0.w * sj) << 16);
    pj.z = f2bf(b1.x * sj) | (f2bf(b1.y * sj) << 16);
    pj.w = f2bf(b1.z * sj) | (f2bf(b1.w * sj) << 16);
    *(uint4*)(Zn + (size_t)i * D_DIM + lane * 8) = pi;
    *(uint4*)(Zn + (size_t)(B_ROWS + i) * D_DIM + lane * 8) = pj;
    if (lane == 0) pos[i] = 20.0f * dt * si * sj;  // positive logit counted twice: 2*dot/T
}

// ---------------- K2: symmetric fused S = Zn·Zn^T + per-row sum(exp(S/T)) -----------------
// 256x256 tile pair (I<=J) per block; 512 threads = 8 waves (2M x 4N), wave tile 128x64.
// Double-buffered LDS (2 x 64 KiB), BK=64, hand-placed pipeline:
//   [vmcnt(0): my previous stage landed] -> [raw s_barrier: everyone's landed]
//   -> [issue next chunk's global_load_lds] -> [compute current chunk]
// so each stage has a full compute phase (~2500 cy of MFMA per CU) to cover load latency.
// sched_barrier(0) pins the region boundaries. XOR-swizzled LDS (slot ^= row&7), linear
// gload_lds dest + pre-swizzled global source + swizzled ds_read (both-sides rule).
__global__ __launch_bounds__(512, 2) void k_gemm_lse(const unsigned short* __restrict__ Zn,
                                                     float* __restrict__ rowsum_g) {
    __shared__ __align__(16) unsigned short lds[2 * 2 * BM * BK];  // 128 KiB: [buf][A/B]
    const int t    = threadIdx.x;
    const int lane = t & 63;
    const int w    = t >> 6;
    const int wm   = w >> 2, wn = w & 3;          // 2 x 4 wave grid
    const int l15  = lane & 15, lhi = lane >> 4;

    // XCD-aware swizzle (bijective: NPAIRS % 8 == 0), then triangular decode
    int bid = (blockIdx.x & 7) * (NPAIRS / 8) + (blockIdx.x >> 3);
    int I = 0;
    while (bid >= NT - I) { bid -= NT - I; ++I; }
    const int J = I + bid;
    const int rowB = I * BM, colB = J * BM;
    const bool dg = (I == J);

    // staging: thread t stages 16B of row (h*64 + t>>3), LDS byte = h*8192 + t*16
    // (linear in t => wave-uniform base + lane*16); source k-segment = (t&7) ^ (row&7)
    const int srow = t >> 3;
    const int slot = t & 7;

    auto stage = [&](int buf, int kbase) {
        char* baseA = (char*)lds + buf * 65536;
        char* baseB = baseA + 32768;
        #pragma unroll
        for (int h = 0; h < 4; ++h) {
            const int row  = h * 64 + srow;
            const int kseg = slot ^ (row & 7);
            const unsigned short* ga = Zn + (size_t)(rowB + row) * D_DIM + kbase + kseg * 8;
            GLOAD16(ga, baseA + h * 8192 + t * 16);
            if (!dg) {
                const unsigned short* gb = Zn + (size_t)(colB + row) * D_DIM + kbase + kseg * 8;
                GLOAD16(gb, baseB + h * 8192 + t * 16);
            }
        }
    };

    f32x4 acc[8][4];
    #pragma unroll
    for (int a = 0; a < 8; ++a)
        #pragma unroll
        for (int b = 0; b < 4; ++b)
            #pragma unroll
            for (int q = 0; q < 4; ++q) acc[a][b][q] = 0.0f;

    // prologue: chunk 0 into buf 0
    stage(0, 0);

    for (int kc = 0; kc < KCHUNKS; ++kc) {
        asm volatile("s_waitcnt vmcnt(0)" ::: "memory");   // my stage(kc) landed
        __builtin_amdgcn_sched_barrier(0);
        __builtin_amdgcn_s_barrier();                      // everyone's stage(kc) landed
        __builtin_amdgcn_sched_barrier(0);
        if (kc + 1 < KCHUNKS) stage((kc + 1) & 1, (kc + 1) * BK);
        __builtin_amdgcn_sched_barrier(0);

        const char* baseA = (const char*)lds + (kc & 1) * 65536;
        const char* baseB = dg ? baseA : baseA + 32768;
        #pragma unroll
        for (int ks = 0; ks < 2; ++ks) {
            bf16x8 af[8], bg[4];
            #pragma unroll
            for (int mi = 0; mi < 8; ++mi) {
                const int row   = wm * 128 + mi * 16 + l15;
                const int slotr = (ks * 4 + lhi) ^ (row & 7);   // swizzled read
                af[mi] = *(const bf16x8*)(baseA + row * 128 + slotr * 16);
            }
            #pragma unroll
            for (int ni = 0; ni < 4; ++ni) {
                const int row   = wn * 64 + ni * 16 + l15;
                const int slotr = (ks * 4 + lhi) ^ (row & 7);
                bg[ni] = *(const bf16x8*)(baseB + row * 128 + slotr * 16);
            }
            #pragma unroll
            for (int mi = 0; mi < 8; ++mi)
                #pragma unroll
                for (int ni = 0; ni < 4; ++ni)
                    acc[mi][ni] = __builtin_amdgcn_mfma_f32_16x16x32_bf16(af[mi], bg[ni], acc[mi][ni], 0, 0, 0);
        }
        __builtin_amdgcn_sched_barrier(0);
    }

    // epilogue: e = exp2(S * 10*log2e); C/D layout: col=lane&15, row=(lane>>4)*4+reg
    float colsum[4] = {0.0f, 0.0f, 0.0f, 0.0f};
    #pragma unroll
    for (int mi = 0; mi < 8; ++mi) {
        const int growb = rowB + wm * 128 + mi * 16 + lhi * 4;
        float rs[4] = {0.0f, 0.0f, 0.0f, 0.0f};
        if (dg) {
            #pragma unroll
            for (int ni = 0; ni < 4; ++ni) {
                const int gcol = colB + wn * 64 + ni * 16 + l15;
                #pragma unroll
                for (int r = 0; r < 4; ++r) {
                    float arg = acc[mi][ni][r] * SCALE_L2E;
                    if (growb + r == gcol) arg = -1e30f;  // exp2 -> 0 (diagonal mask)
                    rs[r] += exp2f(arg);
                }
            }
        } else {
            #pragma unroll
            for (int ni = 0; ni < 4; ++ni)
                #pragma unroll
                for (int r = 0; r < 4; ++r) {
                    const float e = exp2f(acc[mi][ni][r] * SCALE_L2E);
                    rs[r] += e;
                    colsum[ni] += e;
                }
        }
        // row sums: reduce the 16 lanes sharing lhi; one atomic per (mi, r)
        #pragma unroll
        for (int r = 0; r < 4; ++r) {
            float s = rs[r];
            s += __shfl_xor(s, 1);
            s += __shfl_xor(s, 2);
            s += __shfl_xor(s, 4);
            s += __shfl_xor(s, 8);
            if (l15 == 0) atomicAdd(&rowsum_g[growb + r], s);
        }
    }
    if (!dg) {
        // column sums (symmetry): reduce across lhi groups; lanes lhi==0 hold col l15
        #pragma unroll
        for (int ni = 0; ni < 4; ++ni) {
            float c = colsum[ni];
            c += __shfl_xor(c, 16);
            c += __shfl_xor(c, 32);
            if (lhi == 0)
                atomicAdd(&rowsum_g[colB + wn * 64 + ni * 16 + l15], c);
        }
    }
}

// ---------------- K3: sums[1] += sum(ln(rowsum_i)); sums[0] += sum(pos) ----------------
__global__ __launch_bounds__(256) void k_lse(const float* __restrict__ rowsum_g,
                                             const float* __restrict__ pos,
                                             float* __restrict__ sums) {
    const int i = blockIdx.x * 256 + threadIdx.x;
    float l = logf(rowsum_g[i]);
    float p = (i < B_ROWS) ? pos[i] : 0.0f;
    #pragma unroll
    for (int off = 1; off < 64; off <<= 1) {
        l += __shfl_xor(l, off);
        p += __shfl_xor(p, off);
    }
    __shared__ float red[2][4];
    if ((threadIdx.x & 63) == 0) {
        red[0][threadIdx.x >> 6] = l;
        red[1][threadIdx.x >> 6] = p;
    }
    __syncthreads();
    if (threadIdx.x == 0) {
        atomicAdd(&sums[1], red[0][0] + red[0][1] + red[0][2] + red[0][3]);
        atomicAdd(&sums[0], red[1][0] + red[1][1] + red[1][2] + red[1][3]);
    }
}

// ---------------- K4: loss = mean(lse) - mean(pos) ----------------
__global__ void k_final(const float* __restrict__ sums, float* __restrict__ out) {
    out[0] = (sums[1] - sums[0]) * (1.0f / (float)N_ROWS);
}

extern "C" void kernel_launch(void* const* d_in, const int* in_sizes, int n_in,
                              void* d_out, int out_size, void* d_ws, size_t ws_size,
                              hipStream_t stream) {
    (void)in_sizes; (void)n_in; (void)out_size; (void)ws_size;
    const float* zi = (const float*)d_in[0];
    const float* zj = (const float*)d_in[1];

    // workspace layout
    const size_t ZN_BYTES = (size_t)N_ROWS * D_DIM * 2;  // 8 MiB bf16
    unsigned short* Zn    = (unsigned short*)d_ws;
    float* rowsum_g       = (float*)((char*)d_ws + ZN_BYTES);                           // 8192 f32
    float* pos            = (float*)((char*)d_ws + ZN_BYTES + N_ROWS * 4);              // 4096 f32
    float* sums           = (float*)((char*)d_ws + ZN_BYTES + N_ROWS * 4 + B_ROWS * 4); // [pos, lse]

    // zero the atomically-accumulated region (rowsum + pos + sums)
    hipMemsetAsync((char*)d_ws + ZN_BYTES, 0, N_ROWS * 4 + B_ROWS * 4 + 16, stream);

    k_normalize<<<B_ROWS / 4, 256, 0, stream>>>(zi, zj, Zn, pos);
    k_gemm_lse<<<NPAIRS, 512, 0, stream>>>(Zn, rowsum_g);
    k_lse<<<N_ROWS / 256, 256, 0, stream>>>(rowsum_g, pos, sums);
    k_final<<<1, 1, 0, stream>>>(sums, (float*)d_out);
}